// Round 1
// baseline (1106.858 us; speedup 1.0000x reference)
//
#include <hip/hip_runtime.h>
#include <hip/hip_bf16.h>
#include <cstdint>

#define USER_NUM 30000
#define ITEM_NUM 70000
#define NTOT     100000   // USER_NUM + ITEM_NUM

// ---------------------------------------------------------------------------
// CSR build kernels
// ---------------------------------------------------------------------------

__global__ void hist_rows(const int* __restrict__ erow, int* __restrict__ counts, int nnz) {
    int i = blockIdx.x * blockDim.x + threadIdx.x;
    if (i < nnz) atomicAdd(&counts[erow[i]], 1);
}

__global__ void scan_block(const int* __restrict__ counts, int* __restrict__ row_ptr,
                           int* __restrict__ blk_sums, int n) {
    __shared__ int sd[1024];
    int i = blockIdx.x * 1024 + threadIdx.x;
    int v = (i < n) ? counts[i] : 0;
    sd[threadIdx.x] = v;
    __syncthreads();
    for (int off = 1; off < 1024; off <<= 1) {
        int t = (threadIdx.x >= off) ? sd[threadIdx.x - off] : 0;
        __syncthreads();
        sd[threadIdx.x] += t;
        __syncthreads();
    }
    if (i < n) row_ptr[i] = sd[threadIdx.x] - v;   // block-local exclusive
    if (threadIdx.x == 1023) blk_sums[blockIdx.x] = sd[1023];
}

__global__ void scan_sums(int* __restrict__ blk_sums, int nb) {
    __shared__ int sd[128];
    int v = (threadIdx.x < nb) ? blk_sums[threadIdx.x] : 0;
    sd[threadIdx.x] = v;
    __syncthreads();
    for (int off = 1; off < 128; off <<= 1) {
        int t = (threadIdx.x >= off) ? sd[threadIdx.x - off] : 0;
        __syncthreads();
        sd[threadIdx.x] += t;
        __syncthreads();
    }
    if (threadIdx.x < nb) blk_sums[threadIdx.x] = sd[threadIdx.x] - v;  // exclusive
}

__global__ void scan_add(int* __restrict__ row_ptr, const int* __restrict__ blk_sums,
                         int n, int nnz) {
    int i = blockIdx.x * 1024 + threadIdx.x;
    if (i < n) row_ptr[i] += blk_sums[blockIdx.x];
    if (blockIdx.x == 0 && threadIdx.x == 0) row_ptr[n] = nnz;
}

__global__ void scatter_edges(const int* __restrict__ erow, const int* __restrict__ ecol,
                              const float* __restrict__ eval,
                              const int* __restrict__ row_ptr, int* __restrict__ fill,
                              int* __restrict__ scol, float* __restrict__ sval, int nnz) {
    int i = blockIdx.x * blockDim.x + threadIdx.x;
    if (i >= nnz) return;
    int r = erow[i];
    int pos = row_ptr[r] + atomicAdd(&fill[r], 1);
    scol[pos] = ecol[i];
    sval[pos] = eval[i];
}

// ---------------------------------------------------------------------------
// SPMM (CSR): out[r, :] = (ADD_SELF ? x[r,:] : 0) + sum_e val_e * f(x[col_e, :])
// x is the virtual concat: node c -> (c < split ? xa[c] : xb[c - split]), width D.
// ---------------------------------------------------------------------------

template <int D, bool SQ, bool ADD_SELF>
__global__ void spmm_csr(const int* __restrict__ row_ptr,
                         const int* __restrict__ scol,
                         const float* __restrict__ sval,
                         const float* __restrict__ xa,
                         const float* __restrict__ xb,
                         int split, float* __restrict__ out) {
    int r = blockIdx.x;
    int d = threadIdx.x;      // 0..D-1
    float acc = 0.f;
    if (ADD_SELF) {
        const float* self = (r < split) ? xa + (size_t)r * D : xb + (size_t)(r - split) * D;
        acc = self[d];
    }
    int e0 = row_ptr[r], e1 = row_ptr[r + 1];
    for (int e = e0; e < e1; ++e) {
        int c = scol[e];
        float v = sval[e];
        const float* src = (c < split) ? xa + (size_t)c * D : xb + (size_t)(c - split) * D;
        float x = src[d];
        if (SQ) x *= x;
        acc += v * x;
    }
    out[(size_t)r * D + d] = acc;
}

// ---------------------------------------------------------------------------
// Tiled fp32 GEMM: C[m,n] = sum_k A[m,k] * W[n,k] + bias[n]   (+= C if ACC, relu if RELU)
// A: [M,K] row-major, W: [Nout,K] row-major, C: [M,Nout] row-major.
// Block 256 threads, 64x64 tile, BK=16, 4x4 per-thread micro-tile.
// Requires K % 16 == 0 (true for all call sites: 256,128,896,64).
// ---------------------------------------------------------------------------

template <bool ACC, bool RELU>
__global__ __launch_bounds__(256)
void gemm_tn(const float* __restrict__ A, const float* __restrict__ W,
             const float* __restrict__ bias, float* __restrict__ C,
             int M, int K, int Nout) {
    const int BK = 16;
    __shared__ float As[BK][64];
    __shared__ float Ws[BK][64];
    int m0 = blockIdx.y * 64;
    int n0 = blockIdx.x * 64;
    int t = threadIdx.x;
    int tx = t & 15, ty = t >> 4;
    float acc[4][4] = {};
    for (int k0 = 0; k0 < K; k0 += BK) {
#pragma unroll
        for (int i = 0; i < 4; ++i) {
            int l = i * 256 + t;
            int mm = l >> 4;   // 0..63
            int kk = l & 15;
            int gm = m0 + mm;
            As[kk][mm] = (gm < M) ? A[(size_t)gm * K + k0 + kk] : 0.f;
            int gn = n0 + mm;
            Ws[kk][mm] = (gn < Nout) ? W[(size_t)gn * K + k0 + kk] : 0.f;
        }
        __syncthreads();
#pragma unroll
        for (int k = 0; k < BK; ++k) {
            float a[4], w[4];
#pragma unroll
            for (int i = 0; i < 4; ++i) a[i] = As[k][ty * 4 + i];
#pragma unroll
            for (int j = 0; j < 4; ++j) w[j] = Ws[k][tx * 4 + j];
#pragma unroll
            for (int i = 0; i < 4; ++i)
#pragma unroll
                for (int j = 0; j < 4; ++j) acc[i][j] += a[i] * w[j];
        }
        __syncthreads();
    }
#pragma unroll
    for (int i = 0; i < 4; ++i) {
        int gm = m0 + ty * 4 + i;
        if (gm >= M) continue;
#pragma unroll
        for (int j = 0; j < 4; ++j) {
            int gn = n0 + tx * 4 + j;
            if (gn >= Nout) continue;
            float v = acc[i][j] + bias[gn];
            if (ACC) v += C[(size_t)gm * Nout + gn];
            if (RELU) v = fmaxf(v, 0.f);
            C[(size_t)gm * Nout + gn] = v;
        }
    }
}

// ---------------------------------------------------------------------------
// Gather e[b, 0:896] = [final[u], final[it + USER_NUM]] where
// final = [embd(256) | f1(128) | f2(64)]
// ---------------------------------------------------------------------------

__global__ void gather_e(const int* __restrict__ userIdx, const int* __restrict__ itemIdx,
                         const float* __restrict__ uEmbd, const float* __restrict__ iEmbd,
                         const float* __restrict__ f1, const float* __restrict__ f2,
                         float* __restrict__ e) {
    int b = blockIdx.x;
    int u = userIdx[b];
    int g = itemIdx[b] + USER_NUM;
    float* er = e + (size_t)b * 896;
    for (int c = threadIdx.x; c < 896; c += blockDim.x) {
        int node = (c < 448) ? u : g;
        int cc = (c < 448) ? c : c - 448;
        float v;
        if (cc < 256) {
            v = (node < USER_NUM) ? uEmbd[(size_t)node * 256 + cc]
                                  : iEmbd[(size_t)(node - USER_NUM) * 256 + cc];
        } else if (cc < 384) {
            v = f1[(size_t)node * 128 + (cc - 256)];
        } else {
            v = f2[(size_t)node * 64 + (cc - 384)];
        }
        er[c] = v;
    }
}

// out[b] = dot(e2[b, 0:32], T3_W) + T3_b
__global__ void final_mlp(const float* __restrict__ e2, const float* __restrict__ T3_W,
                          const float* __restrict__ T3_b, float* __restrict__ out, int B) {
    int b = blockIdx.x * blockDim.x + threadIdx.x;
    if (b >= B) return;
    float s = T3_b[0];
#pragma unroll
    for (int k = 0; k < 32; ++k) s += e2[(size_t)b * 32 + k] * T3_W[k];
    out[b] = s;
}

// ---------------------------------------------------------------------------

extern "C" void kernel_launch(void* const* d_in, const int* in_sizes, int n_in,
                              void* d_out, int out_size, void* d_ws, size_t ws_size,
                              hipStream_t stream) {
    const int* userIdx  = (const int*)d_in[0];
    const int* itemIdx  = (const int*)d_in[1];
    const int* edge_row = (const int*)d_in[2];
    const int* edge_col = (const int*)d_in[3];
    const float* edge_val = (const float*)d_in[4];
    const float* uEmbd  = (const float*)d_in[5];
    const float* iEmbd  = (const float*)d_in[6];
    const float* W1_0 = (const float*)d_in[7];
    const float* b1_0 = (const float*)d_in[8];
    const float* W2_0 = (const float*)d_in[9];
    const float* b2_0 = (const float*)d_in[10];
    const float* W1_1 = (const float*)d_in[11];
    const float* b1_1 = (const float*)d_in[12];
    const float* W2_1 = (const float*)d_in[13];
    const float* b2_1 = (const float*)d_in[14];
    const float* T1_W = (const float*)d_in[15];
    const float* T1_b = (const float*)d_in[16];
    const float* T2_W = (const float*)d_in[17];
    const float* T2_b = (const float*)d_in[18];
    const float* T3_W = (const float*)d_in[19];
    const float* T3_b = (const float*)d_in[20];
    float* out = (float*)d_out;

    const int B   = in_sizes[0];
    const int NNZ = in_sizes[2];
    const int N   = NTOT;

    // ---- workspace carve-up (bytes, 256-aligned) ----
    uint8_t* ws = (uint8_t*)d_ws;
    size_t off = 0;
    auto alloc = [&](size_t bytes) {
        void* p = ws + off;
        off += (bytes + 255) & ~(size_t)255;
        return p;
    };
    float* acc     = (float*)alloc((size_t)N * 256 * 4);
    float* f1      = (float*)alloc((size_t)N * 128 * 4);
    float* f2      = (float*)alloc((size_t)N * 64 * 4);
    float* ebuf    = (float*)alloc((size_t)B * 896 * 4);
    float* e1      = (float*)alloc((size_t)B * 64 * 4);
    float* e2      = (float*)alloc((size_t)B * 32 * 4);
    int*   counts  = (int*)alloc((size_t)2 * N * 4);       // counts[N] + fill[N] contiguous
    int*   fill    = counts + N;
    int*   row_ptr = (int*)alloc((size_t)(N + 1) * 4);
    int*   blk_sums= (int*)alloc(128 * 4);
    int*   scol    = (int*)alloc((size_t)NNZ * 4);
    float* sval    = (float*)alloc((size_t)NNZ * 4);
    (void)ws_size; (void)n_in; (void)out_size;

    // ---- build CSR ----
    hipMemsetAsync(counts, 0, (size_t)2 * N * 4, stream);
    hist_rows<<<(NNZ + 255) / 256, 256, 0, stream>>>(edge_row, counts, NNZ);
    int nb = (N + 1023) / 1024;   // 98
    scan_block<<<nb, 1024, 0, stream>>>(counts, row_ptr, blk_sums, N);
    scan_sums<<<1, 128, 0, stream>>>(blk_sums, nb);
    scan_add<<<nb, 1024, 0, stream>>>(row_ptr, blk_sums, N, NNZ);
    scatter_edges<<<(NNZ + 255) / 256, 256, 0, stream>>>(edge_row, edge_col, edge_val,
                                                         row_ptr, fill, scol, sval, NNZ);

    // ---- layer 0 (D=256 -> 128) ----
    // acc = spmm(features) + features
    spmm_csr<256, false, true><<<N, 256, 0, stream>>>(row_ptr, scol, sval,
                                                      uEmbd, iEmbd, USER_NUM, acc);
    // f1 = acc @ W1_0^T + b1_0
    {
        dim3 grid((128 + 63) / 64, (N + 63) / 64);
        gemm_tn<false, false><<<grid, 256, 0, stream>>>(acc, W1_0, b1_0, f1, N, 256, 128);
    }
    // acc = spmm(features^2)
    spmm_csr<256, true, false><<<N, 256, 0, stream>>>(row_ptr, scol, sval,
                                                      uEmbd, iEmbd, USER_NUM, acc);
    // f1 += acc @ W2_0^T + b2_0
    {
        dim3 grid((128 + 63) / 64, (N + 63) / 64);
        gemm_tn<true, false><<<grid, 256, 0, stream>>>(acc, W2_0, b2_0, f1, N, 256, 128);
    }

    // ---- layer 1 (D=128 -> 64), input = f1 ----
    spmm_csr<128, false, true><<<N, 128, 0, stream>>>(row_ptr, scol, sval,
                                                      f1, f1, N, acc);
    {
        dim3 grid((64 + 63) / 64, (N + 63) / 64);
        gemm_tn<false, false><<<grid, 256, 0, stream>>>(acc, W1_1, b1_1, f2, N, 128, 64);
    }
    spmm_csr<128, true, false><<<N, 128, 0, stream>>>(row_ptr, scol, sval,
                                                      f1, f1, N, acc);
    {
        dim3 grid((64 + 63) / 64, (N + 63) / 64);
        gemm_tn<true, false><<<grid, 256, 0, stream>>>(acc, W2_1, b2_1, f2, N, 128, 64);
    }

    // ---- gather + MLP ----
    gather_e<<<B, 256, 0, stream>>>(userIdx, itemIdx, uEmbd, iEmbd, f1, f2, ebuf);
    {
        dim3 grid((64 + 63) / 64, (B + 63) / 64);
        gemm_tn<false, true><<<grid, 256, 0, stream>>>(ebuf, T1_W, T1_b, e1, B, 896, 64);
    }
    {
        dim3 grid((32 + 63) / 64, (B + 63) / 64);
        gemm_tn<false, true><<<grid, 256, 0, stream>>>(e1, T2_W, T2_b, e2, B, 64, 32);
    }
    final_mlp<<<(B + 255) / 256, 256, 0, stream>>>(e2, T3_W, T3_b, out, B);
}

// Round 2
// 820.068 us; speedup vs baseline: 1.3497x; 1.3497x over previous
//
#include <hip/hip_runtime.h>
#include <hip/hip_bf16.h>
#include <cstdint>

#define USER_NUM 30000
#define ITEM_NUM 70000
#define NTOT     100000   // USER_NUM + ITEM_NUM

// ---------------------------------------------------------------------------
// CSR build kernels
// ---------------------------------------------------------------------------

__global__ void hist_rows(const int* __restrict__ erow, int* __restrict__ counts, int nnz) {
    int i = blockIdx.x * blockDim.x + threadIdx.x;
    if (i < nnz) atomicAdd(&counts[erow[i]], 1);
}

__global__ void scan_block(const int* __restrict__ counts, int* __restrict__ row_ptr,
                           int* __restrict__ blk_sums, int n) {
    __shared__ int sd[1024];
    int i = blockIdx.x * 1024 + threadIdx.x;
    int v = (i < n) ? counts[i] : 0;
    sd[threadIdx.x] = v;
    __syncthreads();
    for (int off = 1; off < 1024; off <<= 1) {
        int t = (threadIdx.x >= off) ? sd[threadIdx.x - off] : 0;
        __syncthreads();
        sd[threadIdx.x] += t;
        __syncthreads();
    }
    if (i < n) row_ptr[i] = sd[threadIdx.x] - v;   // block-local exclusive
    if (threadIdx.x == 1023) blk_sums[blockIdx.x] = sd[1023];
}

__global__ void scan_sums(int* __restrict__ blk_sums, int nb) {
    __shared__ int sd[128];
    int v = (threadIdx.x < nb) ? blk_sums[threadIdx.x] : 0;
    sd[threadIdx.x] = v;
    __syncthreads();
    for (int off = 1; off < 128; off <<= 1) {
        int t = (threadIdx.x >= off) ? sd[threadIdx.x - off] : 0;
        __syncthreads();
        sd[threadIdx.x] += t;
        __syncthreads();
    }
    if (threadIdx.x < nb) blk_sums[threadIdx.x] = sd[threadIdx.x] - v;  // exclusive
}

__global__ void scan_add(int* __restrict__ row_ptr, const int* __restrict__ blk_sums,
                         int n, int nnz) {
    int i = blockIdx.x * 1024 + threadIdx.x;
    if (i < n) row_ptr[i] += blk_sums[blockIdx.x];
    if (blockIdx.x == 0 && threadIdx.x == 0) row_ptr[n] = nnz;
}

__global__ void scatter_edges(const int* __restrict__ erow, const int* __restrict__ ecol,
                              const float* __restrict__ eval,
                              const int* __restrict__ row_ptr, int* __restrict__ fill,
                              int* __restrict__ scol, float* __restrict__ sval, int nnz) {
    int i = blockIdx.x * blockDim.x + threadIdx.x;
    if (i >= nnz) return;
    int r = erow[i];
    int pos = row_ptr[r] + atomicAdd(&fill[r], 1);
    scol[pos] = ecol[i];
    sval[pos] = eval[i];
}

// ---------------------------------------------------------------------------
// Fused GEMM.
//   DUAL:  G1 = A @ W1^T ;  H = G1 + (A*A) @ W2^T          (no bias, no relu)
//   !DUAL: C1 = relu?(A @ W1^T + bias)
// A is the virtual row-concat [xa ; xb] split at `split`, rows of length K.
// Block: 256 threads = 16x16; tile TM x TN; micro (TM/16) x (TN/16); BK=16.
// LDS layout [k][m] ([k][n]): fragment reads are contiguous -> ds_read_b128,
// conflict-free; transposed staging stores are <=4-way (cheap).
// ---------------------------------------------------------------------------

template <int TM, int TN, bool DUAL, bool RELU>
__global__ __launch_bounds__(256)
void gemm_k(const float* __restrict__ xa, const float* __restrict__ xb, int split,
            const float* __restrict__ W1, const float* __restrict__ W2,
            const float* __restrict__ bias,
            float* __restrict__ C1, float* __restrict__ C2,
            int M, int K, int Nout) {
    constexpr int BK = 16;
    constexpr int MR = TM / 16;
    constexpr int NR = TN / 16;
    __shared__ float As[BK][TM];
    __shared__ float W1s[BK][TN];
    __shared__ float W2s[DUAL ? BK : 1][TN];

    const int m0 = blockIdx.y * TM;
    const int n0 = blockIdx.x * TN;
    const int t  = threadIdx.x;
    const int tx = t & 15, ty = t >> 4;

    float acc1[MR][NR] = {};
    float acc2[MR][NR] = {};

    for (int k0 = 0; k0 < K; k0 += BK) {
        // ---- stage A tile (TM x BK), transposed into [k][m] ----
        for (int l = t; l < TM * 4; l += 256) {
            int row = l >> 2;          // 0..TM-1
            int kq  = l & 3;           // which float4 along k
            int gm  = m0 + row;
            float4 v = {0.f, 0.f, 0.f, 0.f};
            if (gm < M) {
                const float* src = (gm < split) ? xa + (size_t)gm * K
                                                : xb + (size_t)(gm - split) * K;
                v = *(const float4*)(src + k0 + kq * 4);
            }
            As[kq * 4 + 0][row] = v.x;
            As[kq * 4 + 1][row] = v.y;
            As[kq * 4 + 2][row] = v.z;
            As[kq * 4 + 3][row] = v.w;
        }
        // ---- stage W tiles (TN x BK), transposed into [k][n] ----
        for (int l = t; l < TN * 4; l += 256) {
            int row = l >> 2;
            int kq  = l & 3;
            int gn  = n0 + row;
            float4 v1 = {0.f, 0.f, 0.f, 0.f};
            float4 v2 = {0.f, 0.f, 0.f, 0.f};
            if (gn < Nout) {
                v1 = *(const float4*)(W1 + (size_t)gn * K + k0 + kq * 4);
                if constexpr (DUAL)
                    v2 = *(const float4*)(W2 + (size_t)gn * K + k0 + kq * 4);
            }
            W1s[kq * 4 + 0][row] = v1.x;
            W1s[kq * 4 + 1][row] = v1.y;
            W1s[kq * 4 + 2][row] = v1.z;
            W1s[kq * 4 + 3][row] = v1.w;
            if constexpr (DUAL) {
                W2s[kq * 4 + 0][row] = v2.x;
                W2s[kq * 4 + 1][row] = v2.y;
                W2s[kq * 4 + 2][row] = v2.z;
                W2s[kq * 4 + 3][row] = v2.w;
            }
        }
        __syncthreads();
#pragma unroll 4
        for (int k = 0; k < BK; ++k) {
            float a[MR], asq[MR], w1[NR], w2[NR];
#pragma unroll
            for (int i = 0; i < MR; ++i) {
                a[i] = As[k][ty * MR + i];
                if constexpr (DUAL) asq[i] = a[i] * a[i];
            }
#pragma unroll
            for (int j = 0; j < NR; ++j) {
                w1[j] = W1s[k][tx * NR + j];
                if constexpr (DUAL) w2[j] = W2s[k][tx * NR + j];
            }
#pragma unroll
            for (int i = 0; i < MR; ++i)
#pragma unroll
                for (int j = 0; j < NR; ++j) {
                    acc1[i][j] += a[i] * w1[j];
                    if constexpr (DUAL) acc2[i][j] += asq[i] * w2[j];
                }
        }
        __syncthreads();
    }

    // ---- epilogue ----
#pragma unroll
    for (int i = 0; i < MR; ++i) {
        int gm = m0 + ty * MR + i;
        if (gm >= M) continue;
#pragma unroll
        for (int j = 0; j < NR; ++j) {
            int gn = n0 + tx * NR + j;
            if (gn >= Nout) continue;
            size_t o = (size_t)gm * Nout + gn;
            if constexpr (DUAL) {
                float g1 = acc1[i][j];
                C1[o] = g1;
                C2[o] = g1 + acc2[i][j];
            } else {
                float v = acc1[i][j] + bias[gn];
                if constexpr (RELU) v = fmaxf(v, 0.f);
                C1[o] = v;
            }
        }
    }
}

// ---------------------------------------------------------------------------
// Fused SPMM epilogue:
//   out[r,:] = sum_e val_e * H[col_e,:]  +  G1[r,:]  +  biasA + biasB
// One wave per row, VEC floats per lane (width = 64*VEC).
// ---------------------------------------------------------------------------

template <int VEC>
__global__ void spmm_fused(const int* __restrict__ row_ptr,
                           const int* __restrict__ scol,
                           const float* __restrict__ sval,
                           const float* __restrict__ H,
                           const float* __restrict__ G1,
                           const float* __restrict__ biasA,
                           const float* __restrict__ biasB,
                           float* __restrict__ out) {
    constexpr int W = 64 * VEC;
    int r = blockIdx.x;
    int base = threadIdx.x * VEC;
    float acc[VEC];
    const float* g = G1 + (size_t)r * W + base;
#pragma unroll
    for (int v = 0; v < VEC; ++v) acc[v] = g[v] + biasA[base + v] + biasB[base + v];
    int e0 = row_ptr[r], e1 = row_ptr[r + 1];
    for (int e = e0; e < e1; ++e) {
        int c = scol[e];
        float val = sval[e];
        const float* h = H + (size_t)c * W + base;
#pragma unroll
        for (int v = 0; v < VEC; ++v) acc[v] += val * h[v];
    }
    float* o = out + (size_t)r * W + base;
#pragma unroll
    for (int v = 0; v < VEC; ++v) o[v] = acc[v];
}

// ---------------------------------------------------------------------------
// Gather e[b, 0:896] = [final[u], final[it + USER_NUM]],
// final = [embd(256) | f1(128) | f2(64)], float4-vectorized (224 float4/row).
// ---------------------------------------------------------------------------

__global__ void gather_e4(const int* __restrict__ userIdx, const int* __restrict__ itemIdx,
                          const float* __restrict__ uEmbd, const float* __restrict__ iEmbd,
                          const float* __restrict__ f1, const float* __restrict__ f2,
                          float* __restrict__ e) {
    int b = blockIdx.x;
    int u = userIdx[b];
    int g = itemIdx[b] + USER_NUM;
    float4* er = (float4*)(e + (size_t)b * 896);
    for (int q = threadIdx.x; q < 224; q += blockDim.x) {
        int node = (q < 112) ? u : g;
        int cc = ((q < 112) ? q : q - 112) * 4;
        float4 v;
        if (cc < 256) {
            const float* p = (node < USER_NUM) ? uEmbd + (size_t)node * 256 + cc
                                               : iEmbd + (size_t)(node - USER_NUM) * 256 + cc;
            v = *(const float4*)p;
        } else if (cc < 384) {
            v = *(const float4*)(f1 + (size_t)node * 128 + (cc - 256));
        } else {
            v = *(const float4*)(f2 + (size_t)node * 64 + (cc - 384));
        }
        er[q] = v;
    }
}

// out[b] = dot(e2[b, 0:32], T3_W) + T3_b
__global__ void final_mlp(const float* __restrict__ e2, const float* __restrict__ T3_W,
                          const float* __restrict__ T3_b, float* __restrict__ out, int B) {
    int b = blockIdx.x * blockDim.x + threadIdx.x;
    if (b >= B) return;
    float s = T3_b[0];
#pragma unroll
    for (int k = 0; k < 32; ++k) s += e2[(size_t)b * 32 + k] * T3_W[k];
    out[b] = s;
}

// ---------------------------------------------------------------------------

extern "C" void kernel_launch(void* const* d_in, const int* in_sizes, int n_in,
                              void* d_out, int out_size, void* d_ws, size_t ws_size,
                              hipStream_t stream) {
    const int* userIdx  = (const int*)d_in[0];
    const int* itemIdx  = (const int*)d_in[1];
    const int* edge_row = (const int*)d_in[2];
    const int* edge_col = (const int*)d_in[3];
    const float* edge_val = (const float*)d_in[4];
    const float* uEmbd  = (const float*)d_in[5];
    const float* iEmbd  = (const float*)d_in[6];
    const float* W1_0 = (const float*)d_in[7];
    const float* b1_0 = (const float*)d_in[8];
    const float* W2_0 = (const float*)d_in[9];
    const float* b2_0 = (const float*)d_in[10];
    const float* W1_1 = (const float*)d_in[11];
    const float* b1_1 = (const float*)d_in[12];
    const float* W2_1 = (const float*)d_in[13];
    const float* b2_1 = (const float*)d_in[14];
    const float* T1_W = (const float*)d_in[15];
    const float* T1_b = (const float*)d_in[16];
    const float* T2_W = (const float*)d_in[17];
    const float* T2_b = (const float*)d_in[18];
    const float* T3_W = (const float*)d_in[19];
    const float* T3_b = (const float*)d_in[20];
    float* out = (float*)d_out;

    const int B   = in_sizes[0];
    const int NNZ = in_sizes[2];
    const int N   = NTOT;

    // ---- workspace carve-up (bytes, 256-aligned) ----
    uint8_t* ws = (uint8_t*)d_ws;
    size_t off = 0;
    auto alloc = [&](size_t bytes) {
        void* p = ws + off;
        off += (bytes + 255) & ~(size_t)255;
        return p;
    };
    float* bufA = (float*)alloc((size_t)N * 128 * 4);  // G1_0; later G1_1 | H_1
    float* bufB = (float*)alloc((size_t)N * 128 * 4);  // H_0;  later f2
    float* f1   = (float*)alloc((size_t)N * 128 * 4);
    float* ebuf = (float*)alloc((size_t)B * 896 * 4);
    float* e1   = (float*)alloc((size_t)B * 64 * 4);
    float* e2   = (float*)alloc((size_t)B * 32 * 4);
    int*   counts  = (int*)alloc((size_t)2 * N * 4);   // counts[N] + fill[N]
    int*   fill    = counts + N;
    int*   row_ptr = (int*)alloc((size_t)(N + 1) * 4);
    int*   blk_sums= (int*)alloc(128 * 4);
    int*   scol    = (int*)alloc((size_t)NNZ * 4);
    float* sval    = (float*)alloc((size_t)NNZ * 4);
    (void)ws_size; (void)n_in; (void)out_size;

    float* G1_0 = bufA;
    float* H_0  = bufB;
    float* G1_1 = bufA;
    float* H_1  = bufA + (size_t)N * 64;
    float* f2   = bufB;

    // ---- build CSR ----
    hipMemsetAsync(counts, 0, (size_t)2 * N * 4, stream);
    hist_rows<<<(NNZ + 255) / 256, 256, 0, stream>>>(edge_row, counts, NNZ);
    int nb = (N + 1023) / 1024;   // 98
    scan_block<<<nb, 1024, 0, stream>>>(counts, row_ptr, blk_sums, N);
    scan_sums<<<1, 128, 0, stream>>>(blk_sums, nb);
    scan_add<<<nb, 1024, 0, stream>>>(row_ptr, blk_sums, N, NNZ);
    scatter_edges<<<(NNZ + 255) / 256, 256, 0, stream>>>(edge_row, edge_col, edge_val,
                                                         row_ptr, fill, scol, sval, NNZ);

    // ---- layer 0: G1_0 = F@W1_0^T, H_0 = G1_0 + (F*F)@W2_0^T ----
    {
        dim3 grid(1, (N + 127) / 128);
        gemm_k<128, 128, true, false><<<grid, 256, 0, stream>>>(
            uEmbd, iEmbd, USER_NUM, W1_0, W2_0, nullptr, G1_0, H_0, N, 256, 128);
    }
    // f1 = spmm(H_0) + G1_0 + b1_0 + b2_0
    spmm_fused<2><<<N, 64, 0, stream>>>(row_ptr, scol, sval, H_0, G1_0, b1_0, b2_0, f1);

    // ---- layer 1: G1_1 = f1@W1_1^T, H_1 = G1_1 + (f1*f1)@W2_1^T ----
    {
        dim3 grid(1, (N + 127) / 128);
        gemm_k<128, 64, true, false><<<grid, 256, 0, stream>>>(
            f1, f1, N, W1_1, W2_1, nullptr, G1_1, H_1, N, 128, 64);
    }
    // f2 = spmm(H_1) + G1_1 + b1_1 + b2_1
    spmm_fused<1><<<N, 64, 0, stream>>>(row_ptr, scol, sval, H_1, G1_1, b1_1, b2_1, f2);

    // ---- gather + MLP ----
    gather_e4<<<B, 128, 0, stream>>>(userIdx, itemIdx, uEmbd, iEmbd, f1, f2, ebuf);
    {
        dim3 grid(1, (B + 63) / 64);
        gemm_k<64, 64, false, true><<<grid, 256, 0, stream>>>(
            ebuf, ebuf, B, T1_W, nullptr, T1_b, e1, nullptr, B, 896, 64);
    }
    {
        dim3 grid(1, (B + 63) / 64);
        gemm_k<64, 64, false, true><<<grid, 256, 0, stream>>>(
            e1, e1, B, T2_W, nullptr, T2_b, e2, nullptr, B, 64, 32);
    }
    final_mlp<<<(B + 255) / 256, 256, 0, stream>>>(e2, T3_W, T3_b, out, B);
}

// Round 3
// 667.270 us; speedup vs baseline: 1.6588x; 1.2290x over previous
//
#include <hip/hip_runtime.h>
#include <hip/hip_bf16.h>
#include <cstdint>

#define USER_NUM 30000
#define ITEM_NUM 70000
#define NTOT     100000   // USER_NUM + ITEM_NUM

typedef __attribute__((ext_vector_type(8))) short bf16x8;
typedef __attribute__((ext_vector_type(4))) float f32x4;

// fp32 -> (hi, lo) bf16 pair via truncation; a ~= hi + lo to ~2^-16 rel.
__device__ __forceinline__ void split2(float x, ushort& h, ushort& l) {
    unsigned u = __builtin_bit_cast(unsigned int, x);
    h = (ushort)(u >> 16);
    float hf = __builtin_bit_cast(float, u & 0xffff0000u);
    float lo = x - hf;
    l = (ushort)(__builtin_bit_cast(unsigned int, lo) >> 16);
}
__device__ __forceinline__ float hi_f32(ushort h) {
    return __builtin_bit_cast(float, (unsigned int)h << 16);
}

// ---------------------------------------------------------------------------
// CSR build kernels
// ---------------------------------------------------------------------------

__global__ void hist_rows(const int* __restrict__ erow, int* __restrict__ counts, int nnz) {
    int i = blockIdx.x * blockDim.x + threadIdx.x;
    if (i < nnz) atomicAdd(&counts[erow[i]], 1);
}

__global__ void scan_block(const int* __restrict__ counts, int* __restrict__ row_ptr,
                           int* __restrict__ blk_sums, int n) {
    __shared__ int sd[1024];
    int i = blockIdx.x * 1024 + threadIdx.x;
    int v = (i < n) ? counts[i] : 0;
    sd[threadIdx.x] = v;
    __syncthreads();
    for (int off = 1; off < 1024; off <<= 1) {
        int t = (threadIdx.x >= off) ? sd[threadIdx.x - off] : 0;
        __syncthreads();
        sd[threadIdx.x] += t;
        __syncthreads();
    }
    if (i < n) row_ptr[i] = sd[threadIdx.x] - v;   // block-local exclusive
    if (threadIdx.x == 1023) blk_sums[blockIdx.x] = sd[1023];
}

__global__ void scan_sums(int* __restrict__ blk_sums, int nb) {
    __shared__ int sd[128];
    int v = (threadIdx.x < nb) ? blk_sums[threadIdx.x] : 0;
    sd[threadIdx.x] = v;
    __syncthreads();
    for (int off = 1; off < 128; off <<= 1) {
        int t = (threadIdx.x >= off) ? sd[threadIdx.x - off] : 0;
        __syncthreads();
        sd[threadIdx.x] += t;
        __syncthreads();
    }
    if (threadIdx.x < nb) blk_sums[threadIdx.x] = sd[threadIdx.x] - v;  // exclusive
}

__global__ void scan_add(int* __restrict__ row_ptr, const int* __restrict__ blk_sums,
                         int n, int nnz) {
    int i = blockIdx.x * 1024 + threadIdx.x;
    if (i < n) row_ptr[i] += blk_sums[blockIdx.x];
    if (blockIdx.x == 0 && threadIdx.x == 0) row_ptr[n] = nnz;
}

__global__ void scatter_edges(const int* __restrict__ erow, const int* __restrict__ ecol,
                              const float* __restrict__ eval,
                              const int* __restrict__ row_ptr, int* __restrict__ fill,
                              int* __restrict__ scol, float* __restrict__ sval, int nnz) {
    int i = blockIdx.x * blockDim.x + threadIdx.x;
    if (i >= nnz) return;
    int r = erow[i];
    int pos = row_ptr[r] + atomicAdd(&fill[r], 1);
    scol[pos] = ecol[i];
    sval[pos] = eval[i];
}

// ---------------------------------------------------------------------------
// Pre-split a weight matrix into hi/lo bf16 arrays (done once per launch).
// ---------------------------------------------------------------------------

__global__ void split_w(const float* __restrict__ W, ushort* __restrict__ Wh,
                        ushort* __restrict__ Wl, int n) {
    int i = blockIdx.x * blockDim.x + threadIdx.x;
    if (i >= n) return;
    ushort h, l;
    split2(W[i], h, l);
    Wh[i] = h;
    Wl[i] = l;
}

// ---------------------------------------------------------------------------
// Dual split-bf16 MFMA GEMM:
//   C1 = A @ W1^T            (fp32-class precision via hi/lo 3-term MFMA)
//   C2 = C1 + (A*A) @ W2^T
// A is virtual row-concat [xa ; xb] split at `split`, rows length K (K%32==0).
// Block 256 = 4 waves (2x2), tile TM x TN, wave tile (TM/2)x(TN/2), BK=32.
// A staged as hi/lo bf16 in LDS; squares rebuilt+split in registers.
// W pre-split to global hi/lo (split_w).  MFMA 16x16x32_bf16.
// LDS layout [row][k] stride 40 ushort: frag reads = b128, ~2-way conflicts.
// ---------------------------------------------------------------------------

template <int TM, int TN>
__global__ __launch_bounds__(256, 1)
void gemm_dual_mfma(const float* __restrict__ xa, const float* __restrict__ xb, int split,
                    const ushort* __restrict__ W1h, const ushort* __restrict__ W1l,
                    const ushort* __restrict__ W2h, const ushort* __restrict__ W2l,
                    float* __restrict__ C1, float* __restrict__ C2,
                    int M, int K, int Nout) {
    constexpr int BK = 32;
    constexpr int SR = BK + 8;            // padded row stride (ushort)
    constexpr int WTM = TM / 2, WTN = TN / 2;
    constexpr int MI = WTM / 16, NI = WTN / 16;
    __shared__ ushort Ah[TM * SR], Al[TM * SR];
    __shared__ ushort B1h[TN * SR], B1l[TN * SR], B2h[TN * SR], B2l[TN * SR];

    const int m0 = blockIdx.y * TM;
    const int n0 = blockIdx.x * TN;
    const int t  = threadIdx.x;
    const int lane = t & 63, w = t >> 6;
    const int wm = w & 1, wn = w >> 1;
    const int lm = lane & 15, lq = lane >> 4;

    f32x4 acc1[MI][NI] = {};
    f32x4 acc2[MI][NI] = {};

    for (int k0 = 0; k0 < K; k0 += BK) {
        // ---- stage A tile (TM x BK) as hi/lo ----
        for (int l = t; l < TM * 8; l += 256) {
            int row = l >> 3, kq = l & 7;
            int gm = m0 + row;
            float4 v = {0.f, 0.f, 0.f, 0.f};
            if (gm < M) {
                const float* src = (gm < split) ? xa + (size_t)gm * K
                                                : xb + (size_t)(gm - split) * K;
                v = *(const float4*)(src + k0 + kq * 4);
            }
            ushort4 hh, ll;
            split2(v.x, hh.x, ll.x);
            split2(v.y, hh.y, ll.y);
            split2(v.z, hh.z, ll.z);
            split2(v.w, hh.w, ll.w);
            *(ushort4*)(Ah + row * SR + kq * 4) = hh;
            *(ushort4*)(Al + row * SR + kq * 4) = ll;
        }
        // ---- stage W tiles (pre-split bf16 in global) ----
        {
            const ushort* gsrc[4] = {W1h, W1l, W2h, W2l};
            ushort* ldst[4] = {B1h, B1l, B2h, B2l};
#pragma unroll
            for (int a = 0; a < 4; ++a) {
                for (int l = t; l < TN * 8; l += 256) {
                    int row = l >> 3, kq = l & 7;
                    int gn = n0 + row;
                    ushort4 v = {0, 0, 0, 0};
                    if (gn < Nout)
                        v = *(const ushort4*)(gsrc[a] + (size_t)gn * K + k0 + kq * 4);
                    *(ushort4*)(ldst[a] + row * SR + kq * 4) = v;
                }
            }
        }
        __syncthreads();

        // ---- b-fragments (kept live across mi loop) ----
        bf16x8 b1h[NI], b1l[NI], b2h[NI], b2l[NI];
#pragma unroll
        for (int ni = 0; ni < NI; ++ni) {
            int off = (wn * WTN + ni * 16 + lm) * SR + lq * 8;
            b1h[ni] = *(const bf16x8*)(B1h + off);
            b1l[ni] = *(const bf16x8*)(B1l + off);
            b2h[ni] = *(const bf16x8*)(B2h + off);
            b2l[ni] = *(const bf16x8*)(B2l + off);
        }
#pragma unroll
        for (int mi = 0; mi < MI; ++mi) {
            int off = (wm * WTM + mi * 16 + lm) * SR + lq * 8;
            bf16x8 ah = *(const bf16x8*)(Ah + off);
            bf16x8 al = *(const bf16x8*)(Al + off);
            bf16x8 ash, asl;
#pragma unroll
            for (int e = 0; e < 8; ++e) {
                float af = hi_f32((ushort)ah[e]) + hi_f32((ushort)al[e]);
                float sq = af * af;
                ushort sh, sl;
                split2(sq, sh, sl);
                ash[e] = (short)sh;
                asl[e] = (short)sl;
            }
#pragma unroll
            for (int ni = 0; ni < NI; ++ni) {
                acc1[mi][ni] = __builtin_amdgcn_mfma_f32_16x16x32_bf16(ah,  b1h[ni], acc1[mi][ni], 0, 0, 0);
                acc1[mi][ni] = __builtin_amdgcn_mfma_f32_16x16x32_bf16(ah,  b1l[ni], acc1[mi][ni], 0, 0, 0);
                acc1[mi][ni] = __builtin_amdgcn_mfma_f32_16x16x32_bf16(al,  b1h[ni], acc1[mi][ni], 0, 0, 0);
                acc2[mi][ni] = __builtin_amdgcn_mfma_f32_16x16x32_bf16(ash, b2h[ni], acc2[mi][ni], 0, 0, 0);
                acc2[mi][ni] = __builtin_amdgcn_mfma_f32_16x16x32_bf16(ash, b2l[ni], acc2[mi][ni], 0, 0, 0);
                acc2[mi][ni] = __builtin_amdgcn_mfma_f32_16x16x32_bf16(asl, b2h[ni], acc2[mi][ni], 0, 0, 0);
            }
        }
        __syncthreads();
    }

    // ---- epilogue: C/D layout col=lane&15, row=lq*4+r (m89-verified) ----
#pragma unroll
    for (int mi = 0; mi < MI; ++mi)
#pragma unroll
        for (int ni = 0; ni < NI; ++ni)
#pragma unroll
            for (int r = 0; r < 4; ++r) {
                int gm = m0 + wm * WTM + mi * 16 + lq * 4 + r;
                int gn = n0 + wn * WTN + ni * 16 + lm;
                if (gm < M && gn < Nout) {
                    size_t o = (size_t)gm * Nout + gn;
                    float g1 = acc1[mi][ni][r];
                    C1[o] = g1;
                    C2[o] = g1 + acc2[mi][ni][r];
                }
            }
}

// ---------------------------------------------------------------------------
// fp32 vector GEMM (used for the small MLP GEMMs only):
//   C1 = relu?(A @ W1^T + bias);  A = [xa;xb] split-concat.
// 64x64 tile, 4x4 micro (known-good from round 1/2 at this size).
// ---------------------------------------------------------------------------

template <int TM, int TN, bool DUAL, bool RELU>
__global__ __launch_bounds__(256)
void gemm_k(const float* __restrict__ xa, const float* __restrict__ xb, int split,
            const float* __restrict__ W1, const float* __restrict__ W2,
            const float* __restrict__ bias,
            float* __restrict__ C1, float* __restrict__ C2,
            int M, int K, int Nout) {
    constexpr int BK = 16;
    constexpr int MR = TM / 16;
    constexpr int NR = TN / 16;
    __shared__ float As[BK][TM];
    __shared__ float W1s[BK][TN];

    const int m0 = blockIdx.y * TM;
    const int n0 = blockIdx.x * TN;
    const int t  = threadIdx.x;
    const int tx = t & 15, ty = t >> 4;

    float acc1[MR][NR] = {};

    for (int k0 = 0; k0 < K; k0 += BK) {
        for (int l = t; l < TM * 4; l += 256) {
            int row = l >> 2;
            int kq  = l & 3;
            int gm  = m0 + row;
            float4 v = {0.f, 0.f, 0.f, 0.f};
            if (gm < M) {
                const float* src = (gm < split) ? xa + (size_t)gm * K
                                                : xb + (size_t)(gm - split) * K;
                v = *(const float4*)(src + k0 + kq * 4);
            }
            As[kq * 4 + 0][row] = v.x;
            As[kq * 4 + 1][row] = v.y;
            As[kq * 4 + 2][row] = v.z;
            As[kq * 4 + 3][row] = v.w;
        }
        for (int l = t; l < TN * 4; l += 256) {
            int row = l >> 2;
            int kq  = l & 3;
            int gn  = n0 + row;
            float4 v1 = {0.f, 0.f, 0.f, 0.f};
            if (gn < Nout)
                v1 = *(const float4*)(W1 + (size_t)gn * K + k0 + kq * 4);
            W1s[kq * 4 + 0][row] = v1.x;
            W1s[kq * 4 + 1][row] = v1.y;
            W1s[kq * 4 + 2][row] = v1.z;
            W1s[kq * 4 + 3][row] = v1.w;
        }
        __syncthreads();
#pragma unroll 4
        for (int k = 0; k < BK; ++k) {
            float a[MR], w1[NR];
#pragma unroll
            for (int i = 0; i < MR; ++i) a[i] = As[k][ty * MR + i];
#pragma unroll
            for (int j = 0; j < NR; ++j) w1[j] = W1s[k][tx * NR + j];
#pragma unroll
            for (int i = 0; i < MR; ++i)
#pragma unroll
                for (int j = 0; j < NR; ++j) acc1[i][j] += a[i] * w1[j];
        }
        __syncthreads();
    }

#pragma unroll
    for (int i = 0; i < MR; ++i) {
        int gm = m0 + ty * MR + i;
        if (gm >= M) continue;
#pragma unroll
        for (int j = 0; j < NR; ++j) {
            int gn = n0 + tx * NR + j;
            if (gn >= Nout) continue;
            size_t o = (size_t)gm * Nout + gn;
            float v = acc1[i][j] + bias[gn];
            if constexpr (RELU) v = fmaxf(v, 0.f);
            C1[o] = v;
        }
    }
}

// ---------------------------------------------------------------------------
// Fused SPMM epilogue:
//   out[r,:] = sum_e val_e * H[col_e,:]  +  G1[r,:]  +  biasA + biasB
// ---------------------------------------------------------------------------

template <int VEC>
__global__ void spmm_fused(const int* __restrict__ row_ptr,
                           const int* __restrict__ scol,
                           const float* __restrict__ sval,
                           const float* __restrict__ H,
                           const float* __restrict__ G1,
                           const float* __restrict__ biasA,
                           const float* __restrict__ biasB,
                           float* __restrict__ out) {
    constexpr int W = 64 * VEC;
    int r = blockIdx.x;
    int base = threadIdx.x * VEC;
    float acc[VEC];
    const float* g = G1 + (size_t)r * W + base;
#pragma unroll
    for (int v = 0; v < VEC; ++v) acc[v] = g[v] + biasA[base + v] + biasB[base + v];
    int e0 = row_ptr[r], e1 = row_ptr[r + 1];
    for (int e = e0; e < e1; ++e) {
        int c = scol[e];
        float val = sval[e];
        const float* h = H + (size_t)c * W + base;
#pragma unroll
        for (int v = 0; v < VEC; ++v) acc[v] += val * h[v];
    }
    float* o = out + (size_t)r * W + base;
#pragma unroll
    for (int v = 0; v < VEC; ++v) o[v] = acc[v];
}

// ---------------------------------------------------------------------------
// Gather e[b, 0:896] = [final[u], final[it + USER_NUM]]
// ---------------------------------------------------------------------------

__global__ void gather_e4(const int* __restrict__ userIdx, const int* __restrict__ itemIdx,
                          const float* __restrict__ uEmbd, const float* __restrict__ iEmbd,
                          const float* __restrict__ f1, const float* __restrict__ f2,
                          float* __restrict__ e) {
    int b = blockIdx.x;
    int u = userIdx[b];
    int g = itemIdx[b] + USER_NUM;
    float4* er = (float4*)(e + (size_t)b * 896);
    for (int q = threadIdx.x; q < 224; q += blockDim.x) {
        int node = (q < 112) ? u : g;
        int cc = ((q < 112) ? q : q - 112) * 4;
        float4 v;
        if (cc < 256) {
            const float* p = (node < USER_NUM) ? uEmbd + (size_t)node * 256 + cc
                                               : iEmbd + (size_t)(node - USER_NUM) * 256 + cc;
            v = *(const float4*)p;
        } else if (cc < 384) {
            v = *(const float4*)(f1 + (size_t)node * 128 + (cc - 256));
        } else {
            v = *(const float4*)(f2 + (size_t)node * 64 + (cc - 384));
        }
        er[q] = v;
    }
}

__global__ void final_mlp(const float* __restrict__ e2, const float* __restrict__ T3_W,
                          const float* __restrict__ T3_b, float* __restrict__ out, int B) {
    int b = blockIdx.x * blockDim.x + threadIdx.x;
    if (b >= B) return;
    float s = T3_b[0];
#pragma unroll
    for (int k = 0; k < 32; ++k) s += e2[(size_t)b * 32 + k] * T3_W[k];
    out[b] = s;
}

// ---------------------------------------------------------------------------

extern "C" void kernel_launch(void* const* d_in, const int* in_sizes, int n_in,
                              void* d_out, int out_size, void* d_ws, size_t ws_size,
                              hipStream_t stream) {
    const int* userIdx  = (const int*)d_in[0];
    const int* itemIdx  = (const int*)d_in[1];
    const int* edge_row = (const int*)d_in[2];
    const int* edge_col = (const int*)d_in[3];
    const float* edge_val = (const float*)d_in[4];
    const float* uEmbd  = (const float*)d_in[5];
    const float* iEmbd  = (const float*)d_in[6];
    const float* W1_0 = (const float*)d_in[7];
    const float* b1_0 = (const float*)d_in[8];
    const float* W2_0 = (const float*)d_in[9];
    const float* b2_0 = (const float*)d_in[10];
    const float* W1_1 = (const float*)d_in[11];
    const float* b1_1 = (const float*)d_in[12];
    const float* W2_1 = (const float*)d_in[13];
    const float* b2_1 = (const float*)d_in[14];
    const float* T1_W = (const float*)d_in[15];
    const float* T1_b = (const float*)d_in[16];
    const float* T2_W = (const float*)d_in[17];
    const float* T2_b = (const float*)d_in[18];
    const float* T3_W = (const float*)d_in[19];
    const float* T3_b = (const float*)d_in[20];
    float* out = (float*)d_out;

    const int B   = in_sizes[0];
    const int NNZ = in_sizes[2];
    const int N   = NTOT;

    // ---- workspace carve-up (bytes, 256-aligned) ----
    uint8_t* ws = (uint8_t*)d_ws;
    size_t off = 0;
    auto alloc = [&](size_t bytes) {
        void* p = ws + off;
        off += (bytes + 255) & ~(size_t)255;
        return p;
    };
    float* bufA = (float*)alloc((size_t)N * 128 * 4);  // G1_0; later G1_1 | H_1
    float* bufB = (float*)alloc((size_t)N * 128 * 4);  // H_0;  later f2
    float* f1   = (float*)alloc((size_t)N * 128 * 4);
    float* ebuf = (float*)alloc((size_t)B * 896 * 4);
    float* e1   = (float*)alloc((size_t)B * 64 * 4);
    float* e2   = (float*)alloc((size_t)B * 32 * 4);
    int*   counts  = (int*)alloc((size_t)2 * N * 4);   // counts[N] + fill[N]
    int*   fill    = counts + N;
    int*   row_ptr = (int*)alloc((size_t)(N + 1) * 4);
    int*   blk_sums= (int*)alloc(128 * 4);
    int*   scol    = (int*)alloc((size_t)NNZ * 4);
    float* sval    = (float*)alloc((size_t)NNZ * 4);
    // pre-split weight matrices (hi/lo bf16 stored as ushort)
    ushort* W10h = (ushort*)alloc(128 * 256 * 2);
    ushort* W10l = (ushort*)alloc(128 * 256 * 2);
    ushort* W20h = (ushort*)alloc(128 * 256 * 2);
    ushort* W20l = (ushort*)alloc(128 * 256 * 2);
    ushort* W11h = (ushort*)alloc(64 * 128 * 2);
    ushort* W11l = (ushort*)alloc(64 * 128 * 2);
    ushort* W21h = (ushort*)alloc(64 * 128 * 2);
    ushort* W21l = (ushort*)alloc(64 * 128 * 2);
    (void)ws_size; (void)n_in; (void)out_size;

    float* G1_0 = bufA;
    float* H_0  = bufB;
    float* G1_1 = bufA;
    float* H_1  = bufA + (size_t)N * 64;
    float* f2   = bufB;

    // ---- build CSR ----
    hipMemsetAsync(counts, 0, (size_t)2 * N * 4, stream);
    hist_rows<<<(NNZ + 255) / 256, 256, 0, stream>>>(edge_row, counts, NNZ);
    int nb = (N + 1023) / 1024;   // 98
    scan_block<<<nb, 1024, 0, stream>>>(counts, row_ptr, blk_sums, N);
    scan_sums<<<1, 128, 0, stream>>>(blk_sums, nb);
    scan_add<<<nb, 1024, 0, stream>>>(row_ptr, blk_sums, N, NNZ);
    scatter_edges<<<(NNZ + 255) / 256, 256, 0, stream>>>(edge_row, edge_col, edge_val,
                                                         row_ptr, fill, scol, sval, NNZ);

    // ---- pre-split weights ----
    split_w<<<(32768 + 255) / 256, 256, 0, stream>>>(W1_0, W10h, W10l, 32768);
    split_w<<<(32768 + 255) / 256, 256, 0, stream>>>(W2_0, W20h, W20l, 32768);
    split_w<<<(8192 + 255) / 256, 256, 0, stream>>>(W1_1, W11h, W11l, 8192);
    split_w<<<(8192 + 255) / 256, 256, 0, stream>>>(W2_1, W21h, W21l, 8192);

    // ---- layer 0: G1_0 = F@W1_0^T, H_0 = G1_0 + (F*F)@W2_0^T  (MFMA) ----
    {
        dim3 grid(1, (N + 127) / 128);
        gemm_dual_mfma<128, 128><<<grid, 256, 0, stream>>>(
            uEmbd, iEmbd, USER_NUM, W10h, W10l, W20h, W20l, G1_0, H_0, N, 256, 128);
    }
    // f1 = spmm(H_0) + G1_0 + b1_0 + b2_0
    spmm_fused<2><<<N, 64, 0, stream>>>(row_ptr, scol, sval, H_0, G1_0, b1_0, b2_0, f1);

    // ---- layer 1: G1_1 = f1@W1_1^T, H_1 = G1_1 + (f1*f1)@W2_1^T  (MFMA) ----
    {
        dim3 grid(1, (N + 127) / 128);
        gemm_dual_mfma<128, 64><<<grid, 256, 0, stream>>>(
            f1, f1, N, W11h, W11l, W21h, W21l, G1_1, H_1, N, 128, 64);
    }
    // f2 = spmm(H_1) + G1_1 + b1_1 + b2_1
    spmm_fused<1><<<N, 64, 0, stream>>>(row_ptr, scol, sval, H_1, G1_1, b1_1, b2_1, f2);

    // ---- gather + MLP ----
    gather_e4<<<B, 128, 0, stream>>>(userIdx, itemIdx, uEmbd, iEmbd, f1, f2, ebuf);
    {
        dim3 grid(1, (B + 63) / 64);
        gemm_k<64, 64, false, true><<<grid, 256, 0, stream>>>(
            ebuf, ebuf, B, T1_W, nullptr, T1_b, e1, nullptr, B, 896, 64);
    }
    {
        dim3 grid(1, (B + 63) / 64);
        gemm_k<64, 64, false, true><<<grid, 256, 0, stream>>>(
            e1, e1, B, T2_W, nullptr, T2_b, e2, nullptr, B, 64, 32);
    }
    final_mlp<<<(B + 255) / 256, 256, 0, stream>>>(e2, T3_W, T3_b, out, B);
}

// Round 4
// 466.677 us; speedup vs baseline: 2.3718x; 1.4298x over previous
//
#include <hip/hip_runtime.h>
#include <hip/hip_bf16.h>
#include <cstdint>

#define USER_NUM 30000
#define ITEM_NUM 70000
#define NTOT     100000   // USER_NUM + ITEM_NUM

typedef __attribute__((ext_vector_type(8))) short bf16x8;
typedef __attribute__((ext_vector_type(8))) ushort u16x8;
typedef __attribute__((ext_vector_type(4))) float f32x4;

// fp32 -> (hi, lo) bf16 pair via truncation; a ~= hi + lo to ~2^-16 rel.
__device__ __forceinline__ void split2(float x, ushort& h, ushort& l) {
    unsigned u = __builtin_bit_cast(unsigned int, x);
    h = (ushort)(u >> 16);
    float hf = __builtin_bit_cast(float, u & 0xffff0000u);
    float lo = x - hf;
    l = (ushort)(__builtin_bit_cast(unsigned int, lo) >> 16);
}

// ---------------------------------------------------------------------------
// CSR build kernels
// ---------------------------------------------------------------------------

__global__ void hist_rows(const int* __restrict__ erow, int* __restrict__ counts, int nnz) {
    int i = blockIdx.x * blockDim.x + threadIdx.x;
    if (i < nnz) atomicAdd(&counts[erow[i]], 1);
}

__global__ void scan_block(const int* __restrict__ counts, int* __restrict__ row_ptr,
                           int* __restrict__ blk_sums, int n) {
    __shared__ int sd[1024];
    int i = blockIdx.x * 1024 + threadIdx.x;
    int v = (i < n) ? counts[i] : 0;
    sd[threadIdx.x] = v;
    __syncthreads();
    for (int off = 1; off < 1024; off <<= 1) {
        int t = (threadIdx.x >= off) ? sd[threadIdx.x - off] : 0;
        __syncthreads();
        sd[threadIdx.x] += t;
        __syncthreads();
    }
    if (i < n) row_ptr[i] = sd[threadIdx.x] - v;   // block-local exclusive
    if (threadIdx.x == 1023) blk_sums[blockIdx.x] = sd[1023];
}

__global__ void scan_sums(int* __restrict__ blk_sums, int nb) {
    __shared__ int sd[128];
    int v = (threadIdx.x < nb) ? blk_sums[threadIdx.x] : 0;
    sd[threadIdx.x] = v;
    __syncthreads();
    for (int off = 1; off < 128; off <<= 1) {
        int t = (threadIdx.x >= off) ? sd[threadIdx.x - off] : 0;
        __syncthreads();
        sd[threadIdx.x] += t;
        __syncthreads();
    }
    if (threadIdx.x < nb) blk_sums[threadIdx.x] = sd[threadIdx.x] - v;  // exclusive
}

__global__ void scan_add(int* __restrict__ row_ptr, const int* __restrict__ blk_sums,
                         int n, int nnz) {
    int i = blockIdx.x * 1024 + threadIdx.x;
    if (i < n) row_ptr[i] += blk_sums[blockIdx.x];
    if (blockIdx.x == 0 && threadIdx.x == 0) row_ptr[n] = nnz;
}

__global__ void scatter_edges(const int* __restrict__ erow, const int* __restrict__ ecol,
                              const float* __restrict__ eval,
                              const int* __restrict__ row_ptr, int* __restrict__ fill,
                              int* __restrict__ scol, float* __restrict__ sval, int nnz) {
    int i = blockIdx.x * blockDim.x + threadIdx.x;
    if (i >= nnz) return;
    int r = erow[i];
    int pos = row_ptr[r] + atomicAdd(&fill[r], 1);
    scol[pos] = ecol[i];
    sval[pos] = eval[i];
}

// ---------------------------------------------------------------------------
// Pre-split a weight matrix into hi/lo bf16 arrays (done once per launch).
// ---------------------------------------------------------------------------

__global__ void split_w(const float* __restrict__ W, ushort* __restrict__ Wh,
                        ushort* __restrict__ Wl, int n) {
    int i = blockIdx.x * blockDim.x + threadIdx.x;
    if (i >= n) return;
    ushort h, l;
    split2(W[i], h, l);
    Wh[i] = h;
    Wl[i] = l;
}

// ---------------------------------------------------------------------------
// Dual split-bf16 MFMA GEMM:
//   C1 = A @ W1^T ;  C2 = C1 + (A*A) @ W2^T     (fp32-class via 3-term MFMA)
// A = virtual row-concat [xa ; xb] split at `split`, rows length KK (ct).
// TM=128 fixed. Block 256 = 4 waves (2x2): wave tile 64 x (TN/2). BK=32.
// LDS: A hi/lo + Asq hi/lo only (40 KB). W fragments load straight from
// global (pre-split, same addrs across blocks -> L1/L2-hit b128 loads).
// ---------------------------------------------------------------------------

template <int TN, int KK>
__global__ __launch_bounds__(256, 2)
void gemm_dual_mfma(const float* __restrict__ xa, const float* __restrict__ xb, int split,
                    const ushort* __restrict__ W1h, const ushort* __restrict__ W1l,
                    const ushort* __restrict__ W2h, const ushort* __restrict__ W2l,
                    float* __restrict__ C1, float* __restrict__ C2,
                    int M, int Nout) {
    constexpr int TM = 128, BK = 32, SR = BK + 8;
    constexpr int NITER = KK / BK;
    constexpr int WTM = 64, WTN = TN / 2;
    constexpr int MI = WTM / 16, NI = WTN / 16;
    __shared__ ushort Ah[TM * SR], Al[TM * SR], Sh[TM * SR], Sl[TM * SR];

    const int m0 = blockIdx.y * TM;
    const int n0 = blockIdx.x * TN;
    const int t  = threadIdx.x;
    const int lane = t & 63, w = t >> 6;
    const int wm = w & 1, wn = w >> 1;
    const int lm = lane & 15, lq = lane >> 4;

    // staging coords: each thread owns (row, 16-wide k-half)
    const int srow = t >> 1, shalf = t & 1;
    const int sgm = m0 + srow;
    const float* srcrow = (sgm < split) ? xa + (size_t)sgm * KK
                                        : xb + (size_t)(sgm - split) * KK;
    const bool svalid = (sgm < M);
    const int sbase = srow * SR + shalf * 16;

    f32x4 acc1[MI][NI] = {};
    f32x4 acc2[MI][NI] = {};

    for (int it = 0; it < NITER; ++it) {
        const int k0 = it * BK;
        // ---- stage A tile: hi/lo of A and of A*A ----
        {
            ushort hb[16], lb[16], shb[16], slb[16];
#pragma unroll
            for (int q = 0; q < 4; ++q) {
                float4 v = {0.f, 0.f, 0.f, 0.f};
                if (svalid) v = *(const float4*)(srcrow + k0 + shalf * 16 + q * 4);
                float ar[4] = {v.x, v.y, v.z, v.w};
#pragma unroll
                for (int j = 0; j < 4; ++j) {
                    int e = q * 4 + j;
                    split2(ar[j], hb[e], lb[e]);
                    float sq = ar[j] * ar[j];
                    split2(sq, shb[e], slb[e]);
                }
            }
            *(u16x8*)(Ah + sbase)     = *(u16x8*)&hb[0];
            *(u16x8*)(Ah + sbase + 8) = *(u16x8*)&hb[8];
            *(u16x8*)(Al + sbase)     = *(u16x8*)&lb[0];
            *(u16x8*)(Al + sbase + 8) = *(u16x8*)&lb[8];
            *(u16x8*)(Sh + sbase)     = *(u16x8*)&shb[0];
            *(u16x8*)(Sh + sbase + 8) = *(u16x8*)&shb[8];
            *(u16x8*)(Sl + sbase)     = *(u16x8*)&slb[0];
            *(u16x8*)(Sl + sbase + 8) = *(u16x8*)&slb[8];
        }
        __syncthreads();

        // ---- B fragments straight from global (L1/L2-hit) ----
        bf16x8 b1h[NI], b1l[NI], b2h[NI], b2l[NI];
#pragma unroll
        for (int ni = 0; ni < NI; ++ni) {
            size_t wo = (size_t)(n0 + wn * WTN + ni * 16 + lm) * KK + k0 + lq * 8;
            b1h[ni] = *(const bf16x8*)(W1h + wo);
            b1l[ni] = *(const bf16x8*)(W1l + wo);
            b2h[ni] = *(const bf16x8*)(W2h + wo);
            b2l[ni] = *(const bf16x8*)(W2l + wo);
        }
#pragma unroll
        for (int mi = 0; mi < MI; ++mi) {
            int off = (wm * WTM + mi * 16 + lm) * SR + lq * 8;
            bf16x8 ah = *(const bf16x8*)(Ah + off);
            bf16x8 al = *(const bf16x8*)(Al + off);
            bf16x8 qh = *(const bf16x8*)(Sh + off);
            bf16x8 ql = *(const bf16x8*)(Sl + off);
#pragma unroll
            for (int ni = 0; ni < NI; ++ni) {
                acc1[mi][ni] = __builtin_amdgcn_mfma_f32_16x16x32_bf16(ah, b1h[ni], acc1[mi][ni], 0, 0, 0);
                acc1[mi][ni] = __builtin_amdgcn_mfma_f32_16x16x32_bf16(ah, b1l[ni], acc1[mi][ni], 0, 0, 0);
                acc1[mi][ni] = __builtin_amdgcn_mfma_f32_16x16x32_bf16(al, b1h[ni], acc1[mi][ni], 0, 0, 0);
                acc2[mi][ni] = __builtin_amdgcn_mfma_f32_16x16x32_bf16(qh, b2h[ni], acc2[mi][ni], 0, 0, 0);
                acc2[mi][ni] = __builtin_amdgcn_mfma_f32_16x16x32_bf16(qh, b2l[ni], acc2[mi][ni], 0, 0, 0);
                acc2[mi][ni] = __builtin_amdgcn_mfma_f32_16x16x32_bf16(ql, b2h[ni], acc2[mi][ni], 0, 0, 0);
            }
        }
        __syncthreads();
    }

    // ---- epilogue: C/D layout col=lane&15, row=lq*4+r ----
#pragma unroll
    for (int mi = 0; mi < MI; ++mi)
#pragma unroll
        for (int ni = 0; ni < NI; ++ni)
#pragma unroll
            for (int r = 0; r < 4; ++r) {
                int gm = m0 + wm * WTM + mi * 16 + lq * 4 + r;
                int gn = n0 + wn * WTN + ni * 16 + lm;
                if (gm < M && gn < Nout) {
                    size_t o = (size_t)gm * Nout + gn;
                    float g1 = acc1[mi][ni][r];
                    C1[o] = g1;
                    C2[o] = g1 + acc2[mi][ni][r];
                }
            }
}

// ---------------------------------------------------------------------------
// Single-output split-bf16 MFMA GEMM: C = relu(A @ W^T + bias).
// Same structure as dual minus the square path. Used for T1 (K=896).
// ---------------------------------------------------------------------------

template <int TN, int KK>
__global__ __launch_bounds__(256, 2)
void gemm_single_mfma(const float* __restrict__ A,
                      const ushort* __restrict__ Wh, const ushort* __restrict__ Wl,
                      const float* __restrict__ bias, float* __restrict__ C,
                      int M, int Nout) {
    constexpr int TM = 128, BK = 32, SR = BK + 8;
    constexpr int NITER = KK / BK;
    constexpr int WTM = 64, WTN = TN / 2;
    constexpr int MI = WTM / 16, NI = WTN / 16;
    __shared__ ushort Ah[TM * SR], Al[TM * SR];

    const int m0 = blockIdx.y * TM;
    const int n0 = blockIdx.x * TN;
    const int t  = threadIdx.x;
    const int lane = t & 63, w = t >> 6;
    const int wm = w & 1, wn = w >> 1;
    const int lm = lane & 15, lq = lane >> 4;

    const int srow = t >> 1, shalf = t & 1;
    const int sgm = m0 + srow;
    const float* srcrow = A + (size_t)sgm * KK;
    const bool svalid = (sgm < M);
    const int sbase = srow * SR + shalf * 16;

    f32x4 acc[MI][NI] = {};

    for (int it = 0; it < NITER; ++it) {
        const int k0 = it * BK;
        {
            ushort hb[16], lb[16];
#pragma unroll
            for (int q = 0; q < 4; ++q) {
                float4 v = {0.f, 0.f, 0.f, 0.f};
                if (svalid) v = *(const float4*)(srcrow + k0 + shalf * 16 + q * 4);
                float ar[4] = {v.x, v.y, v.z, v.w};
#pragma unroll
                for (int j = 0; j < 4; ++j) split2(ar[j], hb[q * 4 + j], lb[q * 4 + j]);
            }
            *(u16x8*)(Ah + sbase)     = *(u16x8*)&hb[0];
            *(u16x8*)(Ah + sbase + 8) = *(u16x8*)&hb[8];
            *(u16x8*)(Al + sbase)     = *(u16x8*)&lb[0];
            *(u16x8*)(Al + sbase + 8) = *(u16x8*)&lb[8];
        }
        __syncthreads();

        bf16x8 bh[NI], bl[NI];
#pragma unroll
        for (int ni = 0; ni < NI; ++ni) {
            size_t wo = (size_t)(n0 + wn * WTN + ni * 16 + lm) * KK + k0 + lq * 8;
            bh[ni] = *(const bf16x8*)(Wh + wo);
            bl[ni] = *(const bf16x8*)(Wl + wo);
        }
#pragma unroll
        for (int mi = 0; mi < MI; ++mi) {
            int off = (wm * WTM + mi * 16 + lm) * SR + lq * 8;
            bf16x8 ah = *(const bf16x8*)(Ah + off);
            bf16x8 al = *(const bf16x8*)(Al + off);
#pragma unroll
            for (int ni = 0; ni < NI; ++ni) {
                acc[mi][ni] = __builtin_amdgcn_mfma_f32_16x16x32_bf16(ah, bh[ni], acc[mi][ni], 0, 0, 0);
                acc[mi][ni] = __builtin_amdgcn_mfma_f32_16x16x32_bf16(ah, bl[ni], acc[mi][ni], 0, 0, 0);
                acc[mi][ni] = __builtin_amdgcn_mfma_f32_16x16x32_bf16(al, bh[ni], acc[mi][ni], 0, 0, 0);
            }
        }
        __syncthreads();
    }

#pragma unroll
    for (int mi = 0; mi < MI; ++mi)
#pragma unroll
        for (int ni = 0; ni < NI; ++ni)
#pragma unroll
            for (int r = 0; r < 4; ++r) {
                int gm = m0 + wm * WTM + mi * 16 + lq * 4 + r;
                int gn = n0 + wn * WTN + ni * 16 + lm;
                if (gm < M && gn < Nout)
                    C[(size_t)gm * Nout + gn] = fmaxf(acc[mi][ni][r] + bias[gn], 0.f);
            }
}

// ---------------------------------------------------------------------------
// fp32 vector GEMM (small MLP GEMMs): C1 = relu?(A @ W1^T + bias)
// ---------------------------------------------------------------------------

template <int TM, int TN, bool RELU>
__global__ __launch_bounds__(256)
void gemm_k(const float* __restrict__ A, const float* __restrict__ W1,
            const float* __restrict__ bias, float* __restrict__ C1,
            int M, int K, int Nout) {
    constexpr int BK = 16;
    constexpr int MR = TM / 16;
    constexpr int NR = TN / 16;
    __shared__ float As[BK][TM];
    __shared__ float W1s[BK][TN];

    const int m0 = blockIdx.y * TM;
    const int n0 = blockIdx.x * TN;
    const int t  = threadIdx.x;
    const int tx = t & 15, ty = t >> 4;

    float acc1[MR][NR] = {};

    for (int k0 = 0; k0 < K; k0 += BK) {
        for (int l = t; l < TM * 4; l += 256) {
            int row = l >> 2, kq = l & 3;
            int gm = m0 + row;
            float4 v = {0.f, 0.f, 0.f, 0.f};
            if (gm < M) v = *(const float4*)(A + (size_t)gm * K + k0 + kq * 4);
            As[kq * 4 + 0][row] = v.x;
            As[kq * 4 + 1][row] = v.y;
            As[kq * 4 + 2][row] = v.z;
            As[kq * 4 + 3][row] = v.w;
        }
        for (int l = t; l < TN * 4; l += 256) {
            int row = l >> 2, kq = l & 3;
            int gn = n0 + row;
            float4 v1 = {0.f, 0.f, 0.f, 0.f};
            if (gn < Nout) v1 = *(const float4*)(W1 + (size_t)gn * K + k0 + kq * 4);
            W1s[kq * 4 + 0][row] = v1.x;
            W1s[kq * 4 + 1][row] = v1.y;
            W1s[kq * 4 + 2][row] = v1.z;
            W1s[kq * 4 + 3][row] = v1.w;
        }
        __syncthreads();
#pragma unroll 4
        for (int k = 0; k < BK; ++k) {
            float a[MR], w1[NR];
#pragma unroll
            for (int i = 0; i < MR; ++i) a[i] = As[k][ty * MR + i];
#pragma unroll
            for (int j = 0; j < NR; ++j) w1[j] = W1s[k][tx * NR + j];
#pragma unroll
            for (int i = 0; i < MR; ++i)
#pragma unroll
                for (int j = 0; j < NR; ++j) acc1[i][j] += a[i] * w1[j];
        }
        __syncthreads();
    }

#pragma unroll
    for (int i = 0; i < MR; ++i) {
        int gm = m0 + ty * MR + i;
        if (gm >= M) continue;
#pragma unroll
        for (int j = 0; j < NR; ++j) {
            int gn = n0 + tx * NR + j;
            if (gn >= Nout) continue;
            float v = acc1[i][j] + bias[gn];
            if constexpr (RELU) v = fmaxf(v, 0.f);
            C1[(size_t)gm * Nout + gn] = v;
        }
    }
}

// ---------------------------------------------------------------------------
// Fused SPMM epilogue:
//   out[r,:] = sum_e val_e * H[col_e,:]  +  G1[r,:]  +  biasA + biasB
// ---------------------------------------------------------------------------

template <int VEC>
__global__ void spmm_fused(const int* __restrict__ row_ptr,
                           const int* __restrict__ scol,
                           const float* __restrict__ sval,
                           const float* __restrict__ H,
                           const float* __restrict__ G1,
                           const float* __restrict__ biasA,
                           const float* __restrict__ biasB,
                           float* __restrict__ out) {
    constexpr int W = 64 * VEC;
    int r = blockIdx.x;
    int base = threadIdx.x * VEC;
    float acc[VEC];
    const float* g = G1 + (size_t)r * W + base;
#pragma unroll
    for (int v = 0; v < VEC; ++v) acc[v] = g[v] + biasA[base + v] + biasB[base + v];
    int e0 = row_ptr[r], e1 = row_ptr[r + 1];
    for (int e = e0; e < e1; ++e) {
        int c = scol[e];
        float val = sval[e];
        const float* h = H + (size_t)c * W + base;
#pragma unroll
        for (int v = 0; v < VEC; ++v) acc[v] += val * h[v];
    }
    float* o = out + (size_t)r * W + base;
#pragma unroll
    for (int v = 0; v < VEC; ++v) o[v] = acc[v];
}

// ---------------------------------------------------------------------------
// Gather e[b, 0:896] = [final[u], final[it + USER_NUM]]
// ---------------------------------------------------------------------------

__global__ void gather_e4(const int* __restrict__ userIdx, const int* __restrict__ itemIdx,
                          const float* __restrict__ uEmbd, const float* __restrict__ iEmbd,
                          const float* __restrict__ f1, const float* __restrict__ f2,
                          float* __restrict__ e) {
    int b = blockIdx.x;
    int u = userIdx[b];
    int g = itemIdx[b] + USER_NUM;
    float4* er = (float4*)(e + (size_t)b * 896);
    for (int q = threadIdx.x; q < 224; q += blockDim.x) {
        int node = (q < 112) ? u : g;
        int cc = ((q < 112) ? q : q - 112) * 4;
        float4 v;
        if (cc < 256) {
            const float* p = (node < USER_NUM) ? uEmbd + (size_t)node * 256 + cc
                                               : iEmbd + (size_t)(node - USER_NUM) * 256 + cc;
            v = *(const float4*)p;
        } else if (cc < 384) {
            v = *(const float4*)(f1 + (size_t)node * 128 + (cc - 256));
        } else {
            v = *(const float4*)(f2 + (size_t)node * 64 + (cc - 384));
        }
        er[q] = v;
    }
}

__global__ void final_mlp(const float* __restrict__ e2, const float* __restrict__ T3_W,
                          const float* __restrict__ T3_b, float* __restrict__ out, int B) {
    int b = blockIdx.x * blockDim.x + threadIdx.x;
    if (b >= B) return;
    float s = T3_b[0];
#pragma unroll
    for (int k = 0; k < 32; ++k) s += e2[(size_t)b * 32 + k] * T3_W[k];
    out[b] = s;
}

// ---------------------------------------------------------------------------

extern "C" void kernel_launch(void* const* d_in, const int* in_sizes, int n_in,
                              void* d_out, int out_size, void* d_ws, size_t ws_size,
                              hipStream_t stream) {
    const int* userIdx  = (const int*)d_in[0];
    const int* itemIdx  = (const int*)d_in[1];
    const int* edge_row = (const int*)d_in[2];
    const int* edge_col = (const int*)d_in[3];
    const float* edge_val = (const float*)d_in[4];
    const float* uEmbd  = (const float*)d_in[5];
    const float* iEmbd  = (const float*)d_in[6];
    const float* W1_0 = (const float*)d_in[7];
    const float* b1_0 = (const float*)d_in[8];
    const float* W2_0 = (const float*)d_in[9];
    const float* b2_0 = (const float*)d_in[10];
    const float* W1_1 = (const float*)d_in[11];
    const float* b1_1 = (const float*)d_in[12];
    const float* W2_1 = (const float*)d_in[13];
    const float* b2_1 = (const float*)d_in[14];
    const float* T1_W = (const float*)d_in[15];
    const float* T1_b = (const float*)d_in[16];
    const float* T2_W = (const float*)d_in[17];
    const float* T2_b = (const float*)d_in[18];
    const float* T3_W = (const float*)d_in[19];
    const float* T3_b = (const float*)d_in[20];
    float* out = (float*)d_out;

    const int B   = in_sizes[0];
    const int NNZ = in_sizes[2];
    const int N   = NTOT;

    // ---- workspace carve-up (bytes, 256-aligned) ----
    uint8_t* ws = (uint8_t*)d_ws;
    size_t off = 0;
    auto alloc = [&](size_t bytes) {
        void* p = ws + off;
        off += (bytes + 255) & ~(size_t)255;
        return p;
    };
    float* bufA = (float*)alloc((size_t)N * 128 * 4);  // G1_0; later G1_1 | H_1
    float* bufB = (float*)alloc((size_t)N * 128 * 4);  // H_0;  later f2
    float* f1   = (float*)alloc((size_t)N * 128 * 4);
    float* ebuf = (float*)alloc((size_t)B * 896 * 4);
    float* e1   = (float*)alloc((size_t)B * 64 * 4);
    float* e2   = (float*)alloc((size_t)B * 32 * 4);
    int*   counts  = (int*)alloc((size_t)2 * N * 4);   // counts[N] + fill[N]
    int*   fill    = counts + N;
    int*   row_ptr = (int*)alloc((size_t)(N + 1) * 4);
    int*   blk_sums= (int*)alloc(128 * 4);
    int*   scol    = (int*)alloc((size_t)NNZ * 4);
    float* sval    = (float*)alloc((size_t)NNZ * 4);
    // pre-split weight matrices (hi/lo bf16 stored as ushort)
    ushort* W10h = (ushort*)alloc(128 * 256 * 2);
    ushort* W10l = (ushort*)alloc(128 * 256 * 2);
    ushort* W20h = (ushort*)alloc(128 * 256 * 2);
    ushort* W20l = (ushort*)alloc(128 * 256 * 2);
    ushort* W11h = (ushort*)alloc(64 * 128 * 2);
    ushort* W11l = (ushort*)alloc(64 * 128 * 2);
    ushort* W21h = (ushort*)alloc(64 * 128 * 2);
    ushort* W21l = (ushort*)alloc(64 * 128 * 2);
    ushort* T1h  = (ushort*)alloc(64 * 896 * 2);
    ushort* T1l  = (ushort*)alloc(64 * 896 * 2);
    (void)ws_size; (void)n_in; (void)out_size;

    float* G1_0 = bufA;
    float* H_0  = bufB;
    float* G1_1 = bufA;
    float* H_1  = bufA + (size_t)N * 64;
    float* f2   = bufB;

    // ---- build CSR ----
    hipMemsetAsync(counts, 0, (size_t)2 * N * 4, stream);
    hist_rows<<<(NNZ + 255) / 256, 256, 0, stream>>>(edge_row, counts, NNZ);
    int nb = (N + 1023) / 1024;   // 98
    scan_block<<<nb, 1024, 0, stream>>>(counts, row_ptr, blk_sums, N);
    scan_sums<<<1, 128, 0, stream>>>(blk_sums, nb);
    scan_add<<<nb, 1024, 0, stream>>>(row_ptr, blk_sums, N, NNZ);
    scatter_edges<<<(NNZ + 255) / 256, 256, 0, stream>>>(edge_row, edge_col, edge_val,
                                                         row_ptr, fill, scol, sval, NNZ);

    // ---- pre-split weights ----
    split_w<<<(32768 + 255) / 256, 256, 0, stream>>>(W1_0, W10h, W10l, 32768);
    split_w<<<(32768 + 255) / 256, 256, 0, stream>>>(W2_0, W20h, W20l, 32768);
    split_w<<<(8192 + 255) / 256, 256, 0, stream>>>(W1_1, W11h, W11l, 8192);
    split_w<<<(8192 + 255) / 256, 256, 0, stream>>>(W2_1, W21h, W21l, 8192);
    split_w<<<(57344 + 255) / 256, 256, 0, stream>>>(T1_W, T1h, T1l, 57344);

    // ---- layer 0: G1_0 = F@W1_0^T, H_0 = G1_0 + (F*F)@W2_0^T  (MFMA) ----
    {
        dim3 grid(2, (N + 127) / 128);   // TN=64, Nout=128
        gemm_dual_mfma<64, 256><<<grid, 256, 0, stream>>>(
            uEmbd, iEmbd, USER_NUM, W10h, W10l, W20h, W20l, G1_0, H_0, N, 128);
    }
    // f1 = spmm(H_0) + G1_0 + b1_0 + b2_0
    spmm_fused<2><<<N, 64, 0, stream>>>(row_ptr, scol, sval, H_0, G1_0, b1_0, b2_0, f1);

    // ---- layer 1: G1_1 = f1@W1_1^T, H_1 = G1_1 + (f1*f1)@W2_1^T  (MFMA) ----
    {
        dim3 grid(1, (N + 127) / 128);   // TN=64, Nout=64
        gemm_dual_mfma<64, 128><<<grid, 256, 0, stream>>>(
            f1, f1, N, W11h, W11l, W21h, W21l, G1_1, H_1, N, 64);
    }
    // f2 = spmm(H_1) + G1_1 + b1_1 + b2_1
    spmm_fused<1><<<N, 64, 0, stream>>>(row_ptr, scol, sval, H_1, G1_1, b1_1, b2_1, f2);

    // ---- gather + MLP ----
    gather_e4<<<B, 128, 0, stream>>>(userIdx, itemIdx, uEmbd, iEmbd, f1, f2, ebuf);
    {
        dim3 grid(1, (B + 127) / 128);   // TN=64, K=896
        gemm_single_mfma<64, 896><<<grid, 256, 0, stream>>>(ebuf, T1h, T1l, T1_b, e1, B, 64);
    }
    {
        dim3 grid(1, (B + 63) / 64);
        gemm_k<64, 64, true><<<grid, 256, 0, stream>>>(e1, T2_W, T2_b, e2, B, 64, 32);
    }
    final_mlp<<<(B + 255) / 256, 256, 0, stream>>>(e2, T3_W, T3_b, out, B);
}